// Round 8
// baseline (1275.306 us; speedup 1.0000x reference)
//
#include <hip/hip_runtime.h>
#include <math.h>

// FineGrainLoss: B=96, n1=196 (image tokens), n2=77 (text tokens), d=512.
#define BB 96
#define N1 196
#define N2 77
#define DD 512
#define NT 5

#define IMGN (BB * N1 * DD)
#define TXTN (BB * N2 * DD)

// Block = (bt, biPair): TWO bi x one bt. A = 2 x 13 padded strips = 26 tiles,
// B = 5 ct tiles. Per K32 sub: 31 tiles x 64 cells x 16 B = 31,744 B.
// BK=64 step = 62 tiles = 63,488 B LDS. B-read redundancy amortized over 2 bi:
// reads/step 46 (26A + 5B x 4 waves) for 130 MFMAs vs R7's 33 for 65.
#define ATILES 26
#define TILES_SUB 31
#define TILES_STEP 62

typedef _Float16 f16x8 __attribute__((ext_vector_type(8)));  // 8 f16 (4 VGPR)
typedef float f4v __attribute__((ext_vector_type(4)));       // MFMA C/D

typedef unsigned int __attribute__((address_space(1))) as1_uint;
typedef unsigned int __attribute__((address_space(3))) as3_uint;

__device__ __forceinline__ void gload_lds16(const void* g, void* l) {
    __builtin_amdgcn_global_load_lds((const as1_uint*)g, (as3_uint*)l, 16, 0, 0);
}

// fp32 -> fp16 convert pass (4 elems/thread).
__global__ void convert_kernel(const float* __restrict__ src,
                               _Float16* __restrict__ dst, int n) {
    int i = (blockIdx.x * blockDim.x + threadIdx.x) * 4;
    if (i >= n) return;
    float4 v = *(const float4*)(src + i);
    union { _Float16 h[4]; uint2 u; } o;
    o.h[0] = (_Float16)v.x; o.h[1] = (_Float16)v.y;
    o.h[2] = (_Float16)v.z; o.h[3] = (_Float16)v.w;
    *(uint2*)(dst + i) = o.u;
}

// One K=32 sub-step: this wave's NS strips x all 5 cts.
// A strip s at tile s, B ct at tile ATILES+ct.
template <int S0, int NS>
__device__ __forceinline__ void compute_sub(const f16x8* __restrict__ fr,
                                            f4v* __restrict__ acc, int lane) {
    f16x8 b[NT];
#pragma unroll
    for (int ct = 0; ct < NT; ++ct) b[ct] = fr[(ATILES + ct) * 64 + lane];
#pragma unroll
    for (int i = 0; i < NS; ++i) {
        f16x8 a = fr[(S0 + i) * 64 + lane];
#pragma unroll
        for (int ct = 0; ct < NT; ++ct)
            acc[i * NT + ct] = __builtin_amdgcn_mfma_f32_16x16x32_f16(
                a, b[ct], acc[i * NT + ct], 0, 0, 0);
    }
}

// Per-wave reduction partials. C/D layout: col = lane&15, row = (lane>>4)*4+reg.
// rp[strip*16 + row]: strips wave-exclusive. cp[wave*80 + col].
// NO validity masks needed: clamp-padding duplicates real rows/cols, which is
// idempotent under max; the means exclude pads by index range.
template <int S0, int NS>
__device__ __forceinline__ void reduce_phase1(const f4v* __restrict__ acc,
                                              int wave, int lq, int lm,
                                              float* __restrict__ rp,
                                              float* __restrict__ cp) {
    float colm[NT];
#pragma unroll
    for (int ct = 0; ct < NT; ++ct) colm[ct] = -INFINITY;
#pragma unroll
    for (int i = 0; i < NS; ++i) {
        float rowm[4] = {-INFINITY, -INFINITY, -INFINITY, -INFINITY};
#pragma unroll
        for (int ct = 0; ct < NT; ++ct) {
            f4v a = acc[i * NT + ct];
#pragma unroll
            for (int r = 0; r < 4; ++r) {
                rowm[r] = fmaxf(rowm[r], a[r]);
                colm[ct] = fmaxf(colm[ct], a[r]);
            }
        }
#pragma unroll
        for (int r = 0; r < 4; ++r) {
            float m = rowm[r];
            m = fmaxf(m, __shfl_xor(m, 1));
            m = fmaxf(m, __shfl_xor(m, 2));
            m = fmaxf(m, __shfl_xor(m, 4));
            m = fmaxf(m, __shfl_xor(m, 8));
            if (lm == 0) rp[(S0 + i) * 16 + lq * 4 + r] = m;
        }
    }
#pragma unroll
    for (int ct = 0; ct < NT; ++ct) {
        float m = colm[ct];
        m = fmaxf(m, __shfl_xor(m, 16));
        m = fmaxf(m, __shfl_xor(m, 32));
        if (lq == 0) cp[wave * 80 + ct * 16 + lm] = m;
    }
}

// One block per (bt, biPair): S[416x80] = img[2bi-pair].txt[bt]^T, single f16
// MFMA, BK=64 global_load_lds staging (m97 2-barrier), fully fused epilogue
// (writes final i2t rows and t2i entries for both bi — no combine pass).
// __launch_bounds__(256,2): VGPR cap 256 — acc (up to 140 regs) must stay in
// registers; (256,4) caps at 128 and spills acc to scratch (R5: 4.2 GB writes).
template <bool PRE>
__global__ __launch_bounds__(256, 2) void sim_mfma_kernel(
    const float* __restrict__ imgF, const float* __restrict__ txtF,
    const _Float16* __restrict__ h16,   // [img | txt] concatenated
    float* __restrict__ i2t, float* __restrict__ t2i)
{
    const int bt = blockIdx.x, biPair = blockIdx.y;
    const int tid = threadIdx.x;
    const int wave = tid >> 6, lane = tid & 63;
    const int lm = lane & 15;
    const int lq = lane >> 4;

    __shared__ __align__(16) _Float16 lds[TILES_STEP * 64 * 8];   // 63,488 B
    // epilogue scratch aliases the staging tile (K loop fully done first)
    float* rp  = (float*)lds;          // 416: rowmax per padded row
    float* cp  = (float*)lds + 416;    // 320: [wave][80 cols]
    float* sws = (float*)lds + 736;    // 8

    // ---- per-thread staging descriptors (k-invariant element offsets) ----
    // Thread stages cell `lane` of tile T = 4j + wave (62 tiles: waves 0,1
    // do 16 loads, waves 2,3 do 15).
    // T: sub = T/31, T' = T%31; T'<26 -> A (bi_l = T'>=13), else B ct T'-26.
    int off[16];
    const float* fsrc[16];
#pragma unroll
    for (int j = 0; j < 16; ++j) {
        const int T = 4 * j + wave;
        if (T >= TILES_STEP) { off[j] = 0; fsrc[j] = nullptr; continue; }
        const int sub = T / TILES_SUB, Tp = T % TILES_SUB;
        int o;
        bool isA = (Tp < ATILES);
        if (isA) {
            int bi_l = (Tp >= 13);
            int sl = Tp - 13 * bi_l;
            int q = sl * 16 + lm; q = q > (N1 - 1) ? (N1 - 1) : q;
            o = ((2 * biPair + bi_l) * N1 + q) * DD + sub * 32 + lq * 8;
        } else {
            int r = (Tp - ATILES) * 16 + lm; r = r > (N2 - 1) ? (N2 - 1) : r;
            o = (bt * N2 + r) * DD + sub * 32 + lq * 8;
        }
        if constexpr (PRE) {
            off[j] = isA ? o : (IMGN + o);
        } else {
            off[j] = o;
            fsrc[j] = isA ? imgF : txtF;
        }
    }

    f4v acc[35];   // waves 0/2: 35 units (7 strips); waves 1/3: 30 (dead tail)
#pragma unroll
    for (int i = 0; i < 35; ++i) acc[i] = (f4v){0.f, 0.f, 0.f, 0.f};

    const f16x8* frags = (const f16x8*)lds;

    // ---- K loop: 8 steps of BK=64, m97 2-barrier structure ----
#pragma unroll 1
    for (int kc = 0; kc < 8; ++kc) {
        const int k0 = kc * 64;
        if constexpr (PRE) {
#pragma unroll
            for (int j = 0; j < 16; ++j)
                if (4 * j + wave < TILES_STEP)   // wave-uniform guard
                    gload_lds16(h16 + off[j] + k0, lds + (4 * j + wave) * 512);
        } else {
#pragma unroll
            for (int j = 0; j < 16; ++j) {
                if (4 * j + wave < TILES_STEP) {
                    float4 v0 = *(const float4*)(fsrc[j] + off[j] + k0);
                    float4 v1 = *(const float4*)(fsrc[j] + off[j] + k0 + 4);
                    union { f16x8 f; uint4 u; } o;
                    o.f[0] = (_Float16)v0.x; o.f[1] = (_Float16)v0.y;
                    o.f[2] = (_Float16)v0.z; o.f[3] = (_Float16)v0.w;
                    o.f[4] = (_Float16)v1.x; o.f[5] = (_Float16)v1.y;
                    o.f[6] = (_Float16)v1.z; o.f[7] = (_Float16)v1.w;
                    ((uint4*)lds)[(4 * j + wave) * 64 + lane] = o.u;
                }
            }
        }
        __syncthreads();   // staging visible (drains vmcnt/lgkm)
        if (wave == 0) {
            compute_sub<0, 7>(frags, acc, lane);
            compute_sub<0, 7>(frags + TILES_SUB * 64, acc, lane);
        } else if (wave == 1) {
            compute_sub<7, 6>(frags, acc, lane);
            compute_sub<7, 6>(frags + TILES_SUB * 64, acc, lane);
        } else if (wave == 2) {
            compute_sub<13, 7>(frags, acc, lane);
            compute_sub<13, 7>(frags + TILES_SUB * 64, acc, lane);
        } else {
            compute_sub<20, 6>(frags, acc, lane);
            compute_sub<20, 6>(frags + TILES_SUB * 64, acc, lane);
        }
        __syncthreads();   // frag reads done before next overwrite
    }

    // ---- fused reductions (LDS re-used as scratch) ----
    // Strips 0-12 -> bi0 (rows 0-207, q=row), 13-25 -> bi1 (q=row-208).
    if (wave == 0)      reduce_phase1<0, 7>(acc, wave, lq, lm, rp, cp);
    else if (wave == 1) reduce_phase1<7, 6>(acc, wave, lq, lm, rp, cp);
    else if (wave == 2) reduce_phase1<13, 7>(acc, wave, lq, lm, rp, cp);
    else                reduce_phase1<20, 6>(acc, wave, lq, lm, rp, cp);
    __syncthreads();

    // i2t rows: mean over q<196 of rowmax, per bi
    float v0 = (tid < N1) ? rp[tid] : 0.f;
    float v1 = (tid < N1) ? rp[208 + tid] : 0.f;
    v0 += __shfl_xor(v0, 1);  v0 += __shfl_xor(v0, 2);  v0 += __shfl_xor(v0, 4);
    v0 += __shfl_xor(v0, 8);  v0 += __shfl_xor(v0, 16); v0 += __shfl_xor(v0, 32);
    v1 += __shfl_xor(v1, 1);  v1 += __shfl_xor(v1, 2);  v1 += __shfl_xor(v1, 4);
    v1 += __shfl_xor(v1, 8);  v1 += __shfl_xor(v1, 16); v1 += __shfl_xor(v1, 32);
    if (lane == 0) { sws[wave] = v0; sws[4 + wave] = v1; }

    // t2i entries: mean over r<77 of colmax; wave0 -> bi0 (cp rows 0,1),
    // wave1 -> bi1 (cp rows 2,3)
    float tv = 0.f;
    if (wave < 2) {
        const float* a = cp + (wave * 2) * 80;
        const float* b = cp + (wave * 2 + 1) * 80;
        tv = fmaxf(a[lane], b[lane]);
        if (lane < N2 - 64) tv += fmaxf(a[64 + lane], b[64 + lane]);
        tv += __shfl_xor(tv, 1);  tv += __shfl_xor(tv, 2);  tv += __shfl_xor(tv, 4);
        tv += __shfl_xor(tv, 8);  tv += __shfl_xor(tv, 16); tv += __shfl_xor(tv, 32);
    }
    __syncthreads();
    if (tid == 0)
        i2t[(2 * biPair) * BB + bt] =
            (sws[0] + sws[1] + sws[2] + sws[3]) * (1.f / (float)N1);
    if (tid == 1)
        i2t[(2 * biPair + 1) * BB + bt] =
            (sws[4] + sws[5] + sws[6] + sws[7]) * (1.f / (float)N1);
    if (wave < 2 && lane == 0)
        t2i[bt * BB + 2 * biPair + wave] = tv * (1.f / (float)N2);
}

// CE with arange labels over both [B,B] logit matrices.
__global__ __launch_bounds__(256) void ce_kernel(
    const float* __restrict__ i2t, const float* __restrict__ t2i,
    float* __restrict__ out)
{
    const int tid = threadIdx.x;
    const int wid = tid >> 6;
    const int lane = tid & 63;

    float contrib = 0.f;
    if (tid < 2 * BB) {
        const float* M = (tid < BB) ? i2t : t2i;
        const int b = (tid < BB) ? tid : tid - BB;
        const float* row = M + b * BB;
        float mx = row[0];
#pragma unroll 1
        for (int c = 1; c < BB; ++c) mx = fmaxf(mx, row[c]);
        float s = 0.f;
#pragma unroll 1
        for (int c = 0; c < BB; ++c) s += expf(row[c] - mx);
        float lse = mx + logf(s);
        contrib = row[b] - lse;
    }
    contrib += __shfl_xor(contrib, 1);
    contrib += __shfl_xor(contrib, 2);
    contrib += __shfl_xor(contrib, 4);
    contrib += __shfl_xor(contrib, 8);
    contrib += __shfl_xor(contrib, 16);
    contrib += __shfl_xor(contrib, 32);

    __shared__ float s_part[4];
    if (lane == 0) s_part[wid] = contrib;
    __syncthreads();
    if (tid == 0) {
        float total = s_part[0] + s_part[1] + s_part[2] + s_part[3];
        out[0] = -total * (1.f / (float)(2 * BB));
    }
}

extern "C" void kernel_launch(void* const* d_in, const int* in_sizes, int n_in,
                              void* d_out, int out_size, void* d_ws, size_t ws_size,
                              hipStream_t stream) {
    const float* img = (const float*)d_in[0];   // [96,196,512] fp32
    const float* txt = (const float*)d_in[1];   // [96,77,512] fp32
    float* i2t = (float*)d_ws;                  // [96,96]
    float* t2i = i2t + BB * BB;                 // [96,96]

    const size_t conv_off = 2 * BB * BB * sizeof(float);   // 73728, 16B-aligned
    const size_t need = conv_off + (size_t)(IMGN + TXTN) * sizeof(_Float16);

    dim3 grid(BB, BB / 2);   // (bt, biPair)
    if (ws_size >= need) {
        _Float16* h16 = (_Float16*)((char*)d_ws + conv_off);
        convert_kernel<<<(IMGN / 4 + 255) / 256, 256, 0, stream>>>(img, h16, IMGN);
        convert_kernel<<<(TXTN / 4 + 255) / 256, 256, 0, stream>>>(txt, h16 + IMGN, TXTN);
        sim_mfma_kernel<true><<<grid, 256, 0, stream>>>(img, txt, h16, i2t, t2i);
    } else {
        sim_mfma_kernel<false><<<grid, 256, 0, stream>>>(img, txt, nullptr, i2t, t2i);
    }
    ce_kernel<<<1, 256, 0, stream>>>(i2t, t2i, (float*)d_out);
}

// Round 9
// 475.731 us; speedup vs baseline: 2.6807x; 2.6807x over previous
//
#include <hip/hip_runtime.h>
#include <math.h>

// FineGrainLoss: B=96, n1=196 (image tokens), n2=77 (text tokens), d=512.
#define BB 96
#define N1 196
#define N2 77
#define DD 512

#define MT 13   // M tiles of 16 (208 rows, 196 valid)
#define NT 5    // N tiles of 16 (80 cols, 77 valid)

#define IMGN (BB * N1 * DD)
#define TXTN (BB * N2 * DD)

// BK=64 staging: 36 tiles of 64 cells (16 B each = 8 f16 frag slice).
// Tile map: T in [0,36): sub = T/18; T'=T%18; T'<13 -> A strip T'; else B ct T'-13.
#define TILES 36
#define CELLS (TILES * 64)   // 2304 = 9*256

typedef _Float16 f16x8 __attribute__((ext_vector_type(8)));  // 8 f16 (4 VGPR)
typedef float f4v __attribute__((ext_vector_type(4)));       // MFMA C/D

typedef unsigned int __attribute__((address_space(1))) as1_uint;
typedef unsigned int __attribute__((address_space(3))) as3_uint;

__device__ __forceinline__ void gload_lds16(const void* g, void* l) {
    __builtin_amdgcn_global_load_lds((const as1_uint*)g, (as3_uint*)l, 16, 0, 0);
}

// fp32 -> fp16 convert pass (4 elems/thread).
__global__ void convert_kernel(const float* __restrict__ src,
                               _Float16* __restrict__ dst, int n) {
    int i = (blockIdx.x * blockDim.x + threadIdx.x) * 4;
    if (i >= n) return;
    float4 v = *(const float4*)(src + i);
    union { _Float16 h[4]; uint2 u; } o;
    o.h[0] = (_Float16)v.x; o.h[1] = (_Float16)v.y;
    o.h[2] = (_Float16)v.z; o.h[3] = (_Float16)v.w;
    *(uint2*)(dst + i) = o.u;
}

// One K=32 sub-step for wave units [U0,U1), strip-major u = strip*NT + ct.
template <int U0, int U1>
__device__ __forceinline__ void compute_sub(const f16x8* __restrict__ fr,
                                            f4v* __restrict__ acc, int lane) {
    constexpr int S0 = U0 / NT, S1 = (U1 - 1) / NT, NS = S1 - S0 + 1;
    f16x8 bh[NT];
#pragma unroll
    for (int ct = 0; ct < NT; ++ct) bh[ct] = fr[(13 + ct) * 64 + lane];
#pragma unroll
    for (int i = 0; i < NS; ++i) {
        const int s = S0 + i;
        f16x8 ah = fr[s * 64 + lane];
#pragma unroll
        for (int ct = 0; ct < NT; ++ct) {
            const int u = s * NT + ct;
            if (u >= U0 && u < U1)
                acc[u - U0] = __builtin_amdgcn_mfma_f32_16x16x32_f16(
                    ah, bh[ct], acc[u - U0], 0, 0, 0);
        }
    }
}

// Per-wave reduction partials. C/D layout: col = lane&15, row = (lane>>4)*4+reg.
// rp: [13 strips][4 waves][16 rows], cp: [80 cols][4 waves].
template <int U0, int U1>
__device__ __forceinline__ void reduce_phase1(const f4v* __restrict__ acc, int wave,
                                              int lq, int lm,
                                              float* __restrict__ rp,
                                              float* __restrict__ cp) {
    constexpr int S0 = U0 / NT, S1 = (U1 - 1) / NT, NS = S1 - S0 + 1;
    float colm[NT];
#pragma unroll
    for (int ct = 0; ct < NT; ++ct) colm[ct] = -INFINITY;
    float rowm[NS][4];
#pragma unroll
    for (int i = 0; i < NS; ++i)
#pragma unroll
        for (int r = 0; r < 4; ++r) rowm[i][r] = -INFINITY;

#pragma unroll
    for (int u = U0; u < U1; ++u) {
        const int s = u / NT, ct = u % NT;
        f4v a = acc[u - U0];
        bool rows_ok = (s != MT - 1) || (lq == 0);        // rows >=196 invalid
        float cm = fmaxf(fmaxf(a[0], a[1]), fmaxf(a[2], a[3]));
        colm[ct] = fmaxf(colm[ct], rows_ok ? cm : -INFINITY);
        bool col_ok = (ct != NT - 1) || (lm < N2 - 64);   // cols >=77 invalid
#pragma unroll
        for (int r = 0; r < 4; ++r)
            rowm[s - S0][r] = fmaxf(rowm[s - S0][r], col_ok ? a[r] : -INFINITY);
    }
#pragma unroll
    for (int ct = 0; ct < NT; ++ct) {
        float m = colm[ct];
        m = fmaxf(m, __shfl_xor(m, 16));
        m = fmaxf(m, __shfl_xor(m, 32));
        if (lq == 0) cp[(ct * 16 + lm) * 4 + wave] = m;
    }
#pragma unroll
    for (int i = 0; i < NS; ++i) {
#pragma unroll
        for (int r = 0; r < 4; ++r) {
            float m = rowm[i][r];
            m = fmaxf(m, __shfl_xor(m, 1));
            m = fmaxf(m, __shfl_xor(m, 2));
            m = fmaxf(m, __shfl_xor(m, 4));
            m = fmaxf(m, __shfl_xor(m, 8));
            if (lm == 0) rp[(S0 + i) * 64 + wave * 16 + lq * 4 + r] = m;
        }
    }
}

// One block per (bi, bt): S[208x80] = img[bi].txt[bt]^T, single f16 MFMA,
// BK=64 global_load_lds staging (m97 structure), fused max/mean epilogue.
//
// XCD-locality swizzle: working set img+txt = 27 MB fp16 >> 4 MB per-XCD L2,
// so naive dispatch streams ~2.7 GB of staging from L3 (the R6/R7 ~410 us
// plateau: all pipes <25% busy). Remap blockIdx so dispatch-adjacent blocks
// (co-resident, same XCD under id%8 round-robin) share operands:
//   xcd = id%8 owns bi in [xcd*12, xcd*12+12)  -> img slice 2.4 MB, L2-resident
//   groups of 48 blocks cover 4 bt x 12 bi     -> ws 2.7 MB < 4 MB L2
// Worst case (different XCD hash): reverts to ~R6 behavior.
//
// __launch_bounds__(256,2): VGPR cap 256 — acc[17] (68 f32) MUST stay in
// registers; (256,4) caps at 128 and spills acc to scratch (R5: 4.2 GB
// writes). acc > ~20 f4v also spills regardless of cap (R8: acc[35], 3 GB).
template <bool PRE>
__global__ __launch_bounds__(256, 2) void sim_mfma_kernel(
    const float* __restrict__ imgF, const float* __restrict__ txtF,
    const _Float16* __restrict__ h16,   // [img | txt] concatenated
    float* __restrict__ i2t, float* __restrict__ t2i)
{
    // ---- swizzled (bi, bt) ----
    const int id  = blockIdx.x;
    const int xcd = id & 7;
    const int lid = id >> 3;          // 0..1151
    const int btq = lid / 48;         // 0..23: bt quad index
    const int w   = lid % 48;         // 4 bt x 12 bi
    const int bt  = btq * 4 + (w & 3);
    const int bi  = xcd * 12 + (w >> 2);

    const int tid = threadIdx.x;
    const int wave = tid >> 6, lane = tid & 63;
    const int lm = lane & 15;
    const int lq = lane >> 4;

    __shared__ __align__(16) _Float16 lds[CELLS * 8];   // 36,864 B
    // epilogue scratch aliases the staging tile (K loop fully done first)
    float* rp  = (float*)lds;          // 832: [strip][wave][16]
    float* cp  = (float*)lds + 832;    // 320: [col][wave]
    float* sws = (float*)lds + 1152;   // 8

    // ---- per-thread staging descriptors (k-invariant element offsets) ----
    // Thread stages cells of tile T = 4j + wave, cell-in-tile = lane.
    int off[9];
    const float* fsrc[9];
#pragma unroll
    for (int j = 0; j < 9; ++j) {
        const int T = 4 * j + wave;
        const int sub = T / 18, Tp = T % 18;
        int o;
        bool isA = (Tp < 13);
        if (isA) {
            int q = Tp * 16 + lm; q = q > (N1 - 1) ? (N1 - 1) : q;
            o = (bi * N1 + q) * DD + sub * 32 + lq * 8;
        } else {
            int r = (Tp - 13) * 16 + lm; r = r > (N2 - 1) ? (N2 - 1) : r;
            o = (bt * N2 + r) * DD + sub * 32 + lq * 8;
        }
        if constexpr (PRE) {
            off[j] = isA ? o : (IMGN + o);
        } else {
            off[j] = o;
            fsrc[j] = isA ? imgF : txtF;
        }
    }

    f4v acc[17];
#pragma unroll
    for (int i = 0; i < 17; ++i) acc[i] = (f4v){0.f, 0.f, 0.f, 0.f};

    const f16x8* frags = (const f16x8*)lds;

    // ---- K loop: 8 steps of BK=64, m97 2-barrier structure ----
#pragma unroll 1
    for (int kc = 0; kc < 8; ++kc) {
        const int k0 = kc * 64;
        if constexpr (PRE) {
#pragma unroll
            for (int j = 0; j < 9; ++j)
                gload_lds16(h16 + off[j] + k0, lds + (4 * j + wave) * 512);
        } else {
#pragma unroll
            for (int j = 0; j < 9; ++j) {
                float4 v0 = *(const float4*)(fsrc[j] + off[j] + k0);
                float4 v1 = *(const float4*)(fsrc[j] + off[j] + k0 + 4);
                union { f16x8 f; uint4 u; } o;
                o.f[0] = (_Float16)v0.x; o.f[1] = (_Float16)v0.y;
                o.f[2] = (_Float16)v0.z; o.f[3] = (_Float16)v0.w;
                o.f[4] = (_Float16)v1.x; o.f[5] = (_Float16)v1.y;
                o.f[6] = (_Float16)v1.z; o.f[7] = (_Float16)v1.w;
                ((uint4*)lds)[(4 * j + wave) * 64 + lane] = o.u;
            }
        }
        __syncthreads();   // staging visible (drains vmcnt/lgkm)
        if (wave == 0) {
            compute_sub<0, 16>(frags, acc, lane);
            compute_sub<0, 16>(frags + 18 * 64, acc, lane);
        } else if (wave == 1) {
            compute_sub<16, 32>(frags, acc, lane);
            compute_sub<16, 32>(frags + 18 * 64, acc, lane);
        } else if (wave == 2) {
            compute_sub<32, 48>(frags, acc, lane);
            compute_sub<32, 48>(frags + 18 * 64, acc, lane);
        } else {
            compute_sub<48, 65>(frags, acc, lane);
            compute_sub<48, 65>(frags + 18 * 64, acc, lane);
        }
        __syncthreads();   // frag reads done before next overwrite
    }

    // ---- fused reductions (LDS re-used as scratch) ----
    for (int i = tid; i < 832; i += 256) rp[i] = -INFINITY;
    __syncthreads();
    if (wave == 0)      reduce_phase1<0, 16>(acc, wave, lq, lm, rp, cp);
    else if (wave == 1) reduce_phase1<16, 32>(acc, wave, lq, lm, rp, cp);
    else if (wave == 2) reduce_phase1<32, 48>(acc, wave, lq, lm, rp, cp);
    else                reduce_phase1<48, 65>(acc, wave, lq, lm, rp, cp);
    __syncthreads();

    float v = 0.f;
    if (tid < N1) {
        int s = tid >> 4, r = tid & 15;
        float m = rp[s * 64 + r];
        m = fmaxf(m, rp[s * 64 + 16 + r]);
        m = fmaxf(m, rp[s * 64 + 32 + r]);
        m = fmaxf(m, rp[s * 64 + 48 + r]);
        v = m;
    }
    v += __shfl_xor(v, 1);  v += __shfl_xor(v, 2);  v += __shfl_xor(v, 4);
    v += __shfl_xor(v, 8);  v += __shfl_xor(v, 16); v += __shfl_xor(v, 32);
    float cv = 0.f;
    if (tid < N2) {
        cv = fmaxf(fmaxf(cp[tid * 4 + 0], cp[tid * 4 + 1]),
                   fmaxf(cp[tid * 4 + 2], cp[tid * 4 + 3]));
    }
    cv += __shfl_xor(cv, 1);  cv += __shfl_xor(cv, 2);  cv += __shfl_xor(cv, 4);
    cv += __shfl_xor(cv, 8);  cv += __shfl_xor(cv, 16); cv += __shfl_xor(cv, 32);
    if (lane == 0) { sws[wave] = v; sws[4 + wave] = cv; }
    __syncthreads();
    if (tid == 0)
        i2t[bi * BB + bt] = (sws[0] + sws[1] + sws[2] + sws[3]) * (1.f / (float)N1);
    if (tid == 1)
        t2i[bt * BB + bi] = (sws[4] + sws[5] + sws[6] + sws[7]) * (1.f / (float)N2);
}

// CE with arange labels over both [B,B] logit matrices.
__global__ __launch_bounds__(256) void ce_kernel(
    const float* __restrict__ i2t, const float* __restrict__ t2i,
    float* __restrict__ out)
{
    const int tid = threadIdx.x;
    const int wid = tid >> 6;
    const int lane = tid & 63;

    float contrib = 0.f;
    if (tid < 2 * BB) {
        const float* M = (tid < BB) ? i2t : t2i;
        const int b = (tid < BB) ? tid : tid - BB;
        const float* row = M + b * BB;
        float mx = row[0];
#pragma unroll 1
        for (int c = 1; c < BB; ++c) mx = fmaxf(mx, row[c]);
        float s = 0.f;
#pragma unroll 1
        for (int c = 0; c < BB; ++c) s += expf(row[c] - mx);
        float lse = mx + logf(s);
        contrib = row[b] - lse;
    }
    contrib += __shfl_xor(contrib, 1);
    contrib += __shfl_xor(contrib, 2);
    contrib += __shfl_xor(contrib, 4);
    contrib += __shfl_xor(contrib, 8);
    contrib += __shfl_xor(contrib, 16);
    contrib += __shfl_xor(contrib, 32);

    __shared__ float s_part[4];
    if (lane == 0) s_part[wid] = contrib;
    __syncthreads();
    if (tid == 0) {
        float total = s_part[0] + s_part[1] + s_part[2] + s_part[3];
        out[0] = -total * (1.f / (float)(2 * BB));
    }
}

extern "C" void kernel_launch(void* const* d_in, const int* in_sizes, int n_in,
                              void* d_out, int out_size, void* d_ws, size_t ws_size,
                              hipStream_t stream) {
    const float* img = (const float*)d_in[0];   // [96,196,512] fp32
    const float* txt = (const float*)d_in[1];   // [96,77,512] fp32
    float* i2t = (float*)d_ws;                  // [96,96]
    float* t2i = i2t + BB * BB;                 // [96,96]

    const size_t conv_off = 2 * BB * BB * sizeof(float);   // 16B-aligned
    const size_t need = conv_off + (size_t)(IMGN + TXTN) * sizeof(_Float16);

    if (ws_size >= need) {
        _Float16* h16 = (_Float16*)((char*)d_ws + conv_off);
        convert_kernel<<<(IMGN / 4 + 255) / 256, 256, 0, stream>>>(img, h16, IMGN);
        convert_kernel<<<(TXTN / 4 + 255) / 256, 256, 0, stream>>>(txt, h16 + IMGN, TXTN);
        sim_mfma_kernel<true><<<BB * BB, 256, 0, stream>>>(img, txt, h16, i2t, t2i);
    } else {
        sim_mfma_kernel<false><<<BB * BB, 256, 0, stream>>>(img, txt, nullptr, i2t, t2i);
    }
    ce_kernel<<<1, 256, 0, stream>>>(i2t, t2i, (float*)d_out);
}

// Round 10
// 409.442 us; speedup vs baseline: 3.1147x; 1.1619x over previous
//
#include <hip/hip_runtime.h>
#include <math.h>

// FineGrainLoss: B=96, n1=196 (image tokens), n2=77 (text tokens), d=512.
#define BB 96
#define N1 196
#define N2 77
#define DD 512

#define IMGN (BB * N1 * DD)
#define TXTN (BB * N2 * DD)

// Block = (bi, btPair): 208 x 160 tile (13 A strips, 2x5 B ct tiles).
// Tiles are 16 rows x 32 k of f16 = 1 KB = one wave-load.
// Per K32 sub: 13 A + 10 B = 23 tiles; BK=64 step = 46 tiles = 47,104 B.
// Double-buffered: 94,208 B LDS -> 1 block/CU by design (8 waves x ~190 regs
// caps residency at 1 block anyway, so dbuf is free — unlike R3 where it
// halved occupancy).
#define ATILES 13
#define TSUB 23
#define TSTEP 46
#define BUFH (TSTEP * 512)   // _Float16 per buffer

typedef _Float16 f16x8 __attribute__((ext_vector_type(8)));  // 8 f16 (4 VGPR)
typedef float f4v __attribute__((ext_vector_type(4)));       // MFMA C/D

typedef unsigned int __attribute__((address_space(1))) as1_uint;
typedef unsigned int __attribute__((address_space(3))) as3_uint;

__device__ __forceinline__ void gload_lds16(const void* g, void* l) {
    __builtin_amdgcn_global_load_lds((const as1_uint*)g, (as3_uint*)l, 16, 0, 0);
}

// fp32 -> fp16 convert pass (4 elems/thread).
__global__ void convert_kernel(const float* __restrict__ src,
                               _Float16* __restrict__ dst, int n) {
    int i = (blockIdx.x * blockDim.x + threadIdx.x) * 4;
    if (i >= n) return;
    float4 v = *(const float4*)(src + i);
    union { _Float16 h[4]; uint2 u; } o;
    o.h[0] = (_Float16)v.x; o.h[1] = (_Float16)v.y;
    o.h[2] = (_Float16)v.z; o.h[3] = (_Float16)v.w;
    *(uint2*)(dst + i) = o.u;
}

// One K=32 sub-step: wave (g,h) computes strips [SG0, SG0+NS) x 5 cts of
// bt-half H. A strip s at tile s; B ct of half H at tile ATILES + H*5 + ct.
template <int SG0, int NS, int H>
__device__ __forceinline__ void compute_sub(const f16x8* __restrict__ fr,
                                            f4v* __restrict__ acc, int lane) {
    f16x8 b[5];
#pragma unroll
    for (int ct = 0; ct < 5; ++ct)
        b[ct] = fr[(ATILES + H * 5 + ct) * 64 + lane];
#pragma unroll
    for (int i = 0; i < NS; ++i) {
        f16x8 a = fr[(SG0 + i) * 64 + lane];
#pragma unroll
        for (int ct = 0; ct < 5; ++ct)
            acc[i * 5 + ct] = __builtin_amdgcn_mfma_f32_16x16x32_f16(
                a, b[ct], acc[i * 5 + ct], 0, 0, 0);
    }
}

// Reduction partials. C/D layout: col = lane&15, row = (lane>>4)*4 + reg.
// rp[H*208 + q]: per-bt-half rowmax (each (H, strip) owned by one wave).
// cp[g*160 + H*80 + col]: colmax partial per strip-group.
template <int SG0, int NS, int H>
__device__ __forceinline__ void reduce_phase1(const f4v* __restrict__ acc,
                                              int g, int lq, int lm,
                                              float* __restrict__ rp,
                                              float* __restrict__ cp) {
    float colm[5];
#pragma unroll
    for (int ct = 0; ct < 5; ++ct) colm[ct] = -INFINITY;
#pragma unroll
    for (int i = 0; i < NS; ++i) {
        const int s = SG0 + i;
        float rowm[4] = {-INFINITY, -INFINITY, -INFINITY, -INFINITY};
        bool rows_ok = (s != 12) || (lq == 0);   // rows >=196 are clamp-dups
#pragma unroll
        for (int ct = 0; ct < 5; ++ct) {
            f4v a = acc[i * 5 + ct];
            bool col_ok = (ct != 4) || (lm < N2 - 64);   // cols >=77 dups
            float cm = fmaxf(fmaxf(a[0], a[1]), fmaxf(a[2], a[3]));
            colm[ct] = fmaxf(colm[ct], rows_ok ? cm : -INFINITY);
#pragma unroll
            for (int r = 0; r < 4; ++r)
                rowm[r] = fmaxf(rowm[r], col_ok ? a[r] : -INFINITY);
        }
#pragma unroll
        for (int r = 0; r < 4; ++r) {
            float m = rowm[r];
            m = fmaxf(m, __shfl_xor(m, 1));
            m = fmaxf(m, __shfl_xor(m, 2));
            m = fmaxf(m, __shfl_xor(m, 4));
            m = fmaxf(m, __shfl_xor(m, 8));
            if (lm == 0) rp[H * 208 + s * 16 + lq * 4 + r] = m;
        }
    }
#pragma unroll
    for (int ct = 0; ct < 5; ++ct) {
        float m = colm[ct];
        m = fmaxf(m, __shfl_xor(m, 16));
        m = fmaxf(m, __shfl_xor(m, 32));
        if (lq == 0) cp[g * 160 + H * 80 + ct * 16 + lm] = m;
    }
}

// One block per (bi, btPair): S[208x160] = img[bi].(txt[bt0]|txt[bt1])^T.
// 512 threads = 8 waves in a 4x2 grid: strip-groups {4,3,3,3} x bt-half.
// Single f16 MFMA; BK=64 double-buffered global_load_lds staging with
// prefetch-before-compute (one barrier per step); fully fused epilogue.
// __launch_bounds__(512,2): VGPR cap 256. acc[20] (80 f32) must stay in
// registers — WRITE_SIZE ballooning = spill (R5/R8 failure mode).
template <bool PRE>
__global__ __launch_bounds__(512, 2) void sim_mfma_kernel(
    const float* __restrict__ imgF, const float* __restrict__ txtF,
    const _Float16* __restrict__ h16,   // [img | txt] concatenated
    float* __restrict__ i2t, float* __restrict__ t2i)
{
    // ---- XCD-locality swizzle (4608 blocks = 8 xcd x 12 bi x 48 btPairs) ----
    const int id  = blockIdx.x;
    const int xcd = id & 7;
    const int lid = id >> 3;           // 0..575
    const int w   = lid % 48;
    const int btq = lid / 48;          // 0..11
    const int btp = btq * 4 + (w & 3); // 0..47
    const int bi  = xcd * 12 + (w >> 2);
    const int bt0 = btp * 2;

    const int tid = threadIdx.x;
    const int wave = tid >> 6, lane = tid & 63;
    const int lm = lane & 15;
    const int lq = lane >> 4;
    const int g = wave >> 1;           // strip-group 0..3
    // const int h = wave & 1;         // bt-half (baked into templates)

    __shared__ __align__(16) _Float16 lds[2 * BUFH];   // 94,208 B
    // epilogue scratch aliases buffer 0 (K loop fully done first)
    float* rp   = (float*)lds;           // 416: [half][208] rowmax
    float* cp   = (float*)lds + 416;     // 640: [g][160] colmax partials
    float* sws  = (float*)lds + 1056;    // 8
    float* scol = (float*)lds + 1064;    // 160

    // ---- staging descriptors (k-invariant element offsets) ----
    // Thread stages cell `lane` of tile T = 8j + wave (46 tiles; j=5 only
    // for waves 0..5). T: sub = T/23, T' = T%23; T'<13 -> A strip T';
    // else B: ct = T'-13 (0..9), bt = bt0 + (ct>=5).
    int off[6];
    const float* fsrc[6];
#pragma unroll
    for (int j = 0; j < 6; ++j) {
        const int T = 8 * j + wave;
        const int sub = T / TSUB, Tp = T % TSUB;
        int o = 0;
        bool isA = (Tp < ATILES);
        if (T < TSTEP) {
            if (isA) {
                int q = Tp * 16 + lm; q = q > (N1 - 1) ? (N1 - 1) : q;
                o = (bi * N1 + q) * DD + sub * 32 + lq * 8;
            } else {
                int ct = Tp - ATILES;
                int bt = bt0 + (ct >= 5);
                int r = (ct % 5) * 16 + lm; r = r > (N2 - 1) ? (N2 - 1) : r;
                o = (bt * N2 + r) * DD + sub * 32 + lq * 8;
            }
        }
        if constexpr (PRE) {
            off[j] = isA ? o : (IMGN + o);
        } else {
            off[j] = o;
            fsrc[j] = isA ? imgF : txtF;
        }
    }

    auto stage = [&](int kchunk, int b) {
        const int k0 = kchunk * 64;
        if constexpr (PRE) {
#pragma unroll
            for (int j = 0; j < 6; ++j)
                if (8 * j + wave < TSTEP)   // wave-uniform guard
                    gload_lds16(h16 + off[j] + k0,
                                lds + (b * TSTEP + 8 * j + wave) * 512);
        } else {
#pragma unroll
            for (int j = 0; j < 6; ++j) {
                if (8 * j + wave < TSTEP) {
                    float4 v0 = *(const float4*)(fsrc[j] + off[j] + k0);
                    float4 v1 = *(const float4*)(fsrc[j] + off[j] + k0 + 4);
                    union { f16x8 f; uint4 u; } o;
                    o.f[0] = (_Float16)v0.x; o.f[1] = (_Float16)v0.y;
                    o.f[2] = (_Float16)v0.z; o.f[3] = (_Float16)v0.w;
                    o.f[4] = (_Float16)v1.x; o.f[5] = (_Float16)v1.y;
                    o.f[6] = (_Float16)v1.z; o.f[7] = (_Float16)v1.w;
                    ((uint4*)lds)[(b * TSTEP + 8 * j + wave) * 64 + lane] = o.u;
                }
            }
        }
    };

    f4v acc[20];   // waves 0,1 (4-strip group): 20; others: 15 (tail dead)
#pragma unroll
    for (int i = 0; i < 20; ++i) acc[i] = (f4v){0.f, 0.f, 0.f, 0.f};

    auto do_compute = [&](const f16x8* fr) {
        if (wave == 0)      compute_sub<0, 4, 0>(fr, acc, lane);
        else if (wave == 1) compute_sub<0, 4, 1>(fr, acc, lane);
        else if (wave == 2) compute_sub<4, 3, 0>(fr, acc, lane);
        else if (wave == 3) compute_sub<4, 3, 1>(fr, acc, lane);
        else if (wave == 4) compute_sub<7, 3, 0>(fr, acc, lane);
        else if (wave == 5) compute_sub<7, 3, 1>(fr, acc, lane);
        else if (wave == 6) compute_sub<10, 3, 0>(fr, acc, lane);
        else                compute_sub<10, 3, 1>(fr, acc, lane);
    };

    // ---- K loop: 8 steps of BK=64, dbuf, prefetch-before-compute,
    //      ONE barrier per step (drain lands after ~1600 cyc of compute) ----
    stage(0, 0);
    __syncthreads();
#pragma unroll 1
    for (int kc = 0; kc < 8; ++kc) {
        const int cur = kc & 1;
        if (kc + 1 < 8) stage(kc + 1, cur ^ 1);   // async prefetch
        const f16x8* fr = (const f16x8*)(lds + cur * BUFH);
        do_compute(fr);
        do_compute(fr + TSUB * 64);
        __syncthreads();   // reads of cur done + prefetch DMA drained
    }

    // ---- fused reductions (LDS buffer re-used as scratch) ----
    if (wave == 0)      reduce_phase1<0, 4, 0>(acc, g, lq, lm, rp, cp);
    else if (wave == 1) reduce_phase1<0, 4, 1>(acc, g, lq, lm, rp, cp);
    else if (wave == 2) reduce_phase1<4, 3, 0>(acc, g, lq, lm, rp, cp);
    else if (wave == 3) reduce_phase1<4, 3, 1>(acc, g, lq, lm, rp, cp);
    else if (wave == 4) reduce_phase1<7, 3, 0>(acc, g, lq, lm, rp, cp);
    else if (wave == 5) reduce_phase1<7, 3, 1>(acc, g, lq, lm, rp, cp);
    else if (wave == 6) reduce_phase1<10, 3, 0>(acc, g, lq, lm, rp, cp);
    else                reduce_phase1<10, 3, 1>(acc, g, lq, lm, rp, cp);
    __syncthreads();

    // i2t: mean over q<196 of rowmax, per bt-half.
    // Waves 0-3 (tid 0-255) cover half 0; waves 4-7 cover half 1.
    {
        const int half = tid >> 8;
        const int t = tid & 255;
        float v = (t < N1) ? rp[half * 208 + t] : 0.f;
        v += __shfl_xor(v, 1);  v += __shfl_xor(v, 2);  v += __shfl_xor(v, 4);
        v += __shfl_xor(v, 8);  v += __shfl_xor(v, 16); v += __shfl_xor(v, 32);
        if (lane == 0) sws[wave] = v;
    }
    // colmax merge across strip-groups
    if (tid < 160) {
        float m = fmaxf(fmaxf(cp[tid], cp[160 + tid]),
                        fmaxf(cp[320 + tid], cp[480 + tid]));
        scol[tid] = m;
    }
    __syncthreads();
    if (tid == 0)
        i2t[bi * BB + bt0] =
            (sws[0] + sws[1] + sws[2] + sws[3]) * (1.f / (float)N1);
    if (tid == 1)
        i2t[bi * BB + bt0 + 1] =
            (sws[4] + sws[5] + sws[6] + sws[7]) * (1.f / (float)N1);
    // t2i: mean over r<77 of colmax; wave0 -> bt0 (cols 0-79), wave1 -> bt1.
    if (wave < 2) {
        const float* c = scol + wave * 80;
        float cv = c[lane] + ((lane < N2 - 64) ? c[64 + lane] : 0.f);
        cv += __shfl_xor(cv, 1);  cv += __shfl_xor(cv, 2);  cv += __shfl_xor(cv, 4);
        cv += __shfl_xor(cv, 8);  cv += __shfl_xor(cv, 16); cv += __shfl_xor(cv, 32);
        if (lane == 0)
            t2i[(bt0 + wave) * BB + bi] = cv * (1.f / (float)N2);
    }
}

// CE with arange labels over both [B,B] logit matrices.
__global__ __launch_bounds__(256) void ce_kernel(
    const float* __restrict__ i2t, const float* __restrict__ t2i,
    float* __restrict__ out)
{
    const int tid = threadIdx.x;
    const int wid = tid >> 6;
    const int lane = tid & 63;

    float contrib = 0.f;
    if (tid < 2 * BB) {
        const float* M = (tid < BB) ? i2t : t2i;
        const int b = (tid < BB) ? tid : tid - BB;
        const float* row = M + b * BB;
        float mx = row[0];
#pragma unroll 1
        for (int c = 1; c < BB; ++c) mx = fmaxf(mx, row[c]);
        float s = 0.f;
#pragma unroll 1
        for (int c = 0; c < BB; ++c) s += expf(row[c] - mx);
        float lse = mx + logf(s);
        contrib = row[b] - lse;
    }
    contrib += __shfl_xor(contrib, 1);
    contrib += __shfl_xor(contrib, 2);
    contrib += __shfl_xor(contrib, 4);
    contrib += __shfl_xor(contrib, 8);
    contrib += __shfl_xor(contrib, 16);
    contrib += __shfl_xor(contrib, 32);

    __shared__ float s_part[4];
    if (lane == 0) s_part[wid] = contrib;
    __syncthreads();
    if (tid == 0) {
        float total = s_part[0] + s_part[1] + s_part[2] + s_part[3];
        out[0] = -total * (1.f / (float)(2 * BB));
    }
}

extern "C" void kernel_launch(void* const* d_in, const int* in_sizes, int n_in,
                              void* d_out, int out_size, void* d_ws, size_t ws_size,
                              hipStream_t stream) {
    const float* img = (const float*)d_in[0];   // [96,196,512] fp32
    const float* txt = (const float*)d_in[1];   // [96,77,512] fp32
    float* i2t = (float*)d_ws;                  // [96,96]
    float* t2i = i2t + BB * BB;                 // [96,96]

    const size_t conv_off = 2 * BB * BB * sizeof(float);   // 16B-aligned
    const size_t need = conv_off + (size_t)(IMGN + TXTN) * sizeof(_Float16);

    const int nblocks = BB * (BB / 2);   // 4608 = (bi, btPair)
    if (ws_size >= need) {
        _Float16* h16 = (_Float16*)((char*)d_ws + conv_off);
        convert_kernel<<<(IMGN / 4 + 255) / 256, 256, 0, stream>>>(img, h16, IMGN);
        convert_kernel<<<(TXTN / 4 + 255) / 256, 256, 0, stream>>>(txt, h16 + IMGN, TXTN);
        sim_mfma_kernel<true><<<nblocks, 512, 0, stream>>>(img, txt, h16, i2t, t2i);
    } else {
        sim_mfma_kernel<false><<<nblocks, 512, 0, stream>>>(img, txt, nullptr, i2t, t2i);
    }
    ce_kernel<<<1, 256, 0, stream>>>(i2t, t2i, (float*)d_out);
}